// Round 1
// baseline (124.140 us; speedup 1.0000x reference)
//
#include <hip/hip_runtime.h>
#include <hip/hip_bf16.h>
#include <cstdint>
#include <cstddef>

// Problem constants
#define BDIM   32768
#define KDIM   2048
#define NDIM   128
#define VHEADS 20
#define PDIM   6
#define RLORA  10

#define BK      64
#define BM      64
#define NCHUNK  (KDIM / BK)            // 32
#define CHUNK_BYTES (NDIM * BK * 2)    // 16384 bytes of bf16 per W chunk
#define WS_W_BYTES  (KDIM * NDIM * 2)  // 524288
#define OUT_ELEMS   (BDIM * VHEADS * PDIM)  // 3932160

typedef __attribute__((ext_vector_type(8))) __bf16 bf16x8;
typedef __attribute__((ext_vector_type(4))) float f32x4;
typedef __attribute__((ext_vector_type(4))) unsigned int u32x4;

union FragU { bf16x8 b; u32x4 u; };

__device__ __forceinline__ unsigned int cvt_pk_bf16(float lo, float hi) {
  unsigned int r;
  asm("v_cvt_pk_bf16_f32 %0, %1, %2" : "=v"(r) : "v"(lo), "v"(hi));
  return r;
}

__device__ __forceinline__ void gload_lds16(const void* g, void* l) {
  __builtin_amdgcn_global_load_lds(
      (__attribute__((address_space(1))) void*)(g),
      (__attribute__((address_space(3))) void*)(l), 16, 0, 0);
}

__device__ __forceinline__ float fast_tanh(float x) {
  float ax = fabsf(x);
  float e  = __expf(-2.0f * ax);
  float t  = __fdividef(1.0f - e, 1.0f + e);
  return copysignf(t, x);
}

// ---------------------------------------------------------------------------
// k0: prep — (a) We1 f32[2048][128] -> bf16, transposed to Wt[n][k], packed in
// per-chunk LDS-image order with INVERSE XOR-swizzle so that a linear
// global_load_lds produces the swizzled LDS layout.  (b) M = lora_A @ lora_B.
// ---------------------------------------------------------------------------
__global__ __launch_bounds__(256)
void k0_prep(const float* __restrict__ We1,
             const float* __restrict__ lA,
             const float* __restrict__ lB,
             unsigned short* __restrict__ wsw,
             float* __restrict__ wsM) {
  if (blockIdx.x == 1024) {
    int t = threadIdx.x;
    if (t < 2 * VHEADS * PDIM) {
      int d = t / (VHEADS * PDIM);
      int vp = t - d * (VHEADS * PDIM);
      float s = 0.f;
#pragma unroll
      for (int r = 0; r < RLORA; ++r)
        s = fmaf(lA[d * RLORA + r], lB[r * (VHEADS * PDIM) + vp], s);
      wsM[t] = s;  // layout [d][vp]
    }
    return;
  }
  int e = blockIdx.x * 256 + threadIdx.x;   // 0 .. 262143 (bf16 element slot)
  int c  = e >> 13;                         // chunk (8192 elems per chunk)
  int r  = e & 8191;
  int n  = r >> 6;                          // 0..127  (64 k-elems per n row)
  int rb = (r & 63) << 1;                   // byte within 128-B row
  int k  = (rb ^ ((n & 7) << 4)) >> 1;      // un-swizzle
  float v = We1[(size_t)(c * BK + k) * NDIM + n];
  __hip_bfloat16 h = __float2bfloat16(v);
  wsw[e] = *reinterpret_cast<unsigned short*>(&h);
}

// ---------------------------------------------------------------------------
// k1: encoder — h1 = relu(x @ We1 + be1); z = h1 @ We2 + be2  (writes z only)
// 512 blocks x 256 threads (4 waves).  BM=64 rows/block, 16 rows/wave.
// A (x rows): global f32 -> regs -> cvt_pk bf16 fragments (no reuse -> no LDS)
// W: bf16 pre-swizzled in ws, double-buffered LDS via global_load_lds.
// ---------------------------------------------------------------------------
__global__ __launch_bounds__(256, 2)
void k1_encoder(const float* __restrict__ x,
                const unsigned short* __restrict__ wt,
                const float* __restrict__ be1,
                const float* __restrict__ We2,
                const float* __restrict__ be2,
                float* __restrict__ zout) {
  __shared__ char lds[2][CHUNK_BYTES] __attribute__((aligned(16)));

  const int tid  = threadIdx.x;
  const int lane = tid & 63;
  const int wv   = tid >> 6;        // wave 0..3
  const int l15  = lane & 15;
  const int kgrp = lane >> 4;       // 0..3
  const int blk  = blockIdx.x;
  const int rbase = blk * BM + wv * 16;
  const int arow  = rbase + l15;

  const float* aptr = x + (size_t)arow * KDIM + kgrp * 8;
  const char*  wsrc = (const char*)wt;

  // swizzled ds_read byte offsets (within a buffer), per N-tile add nt*2048
  const int x7 = (l15 & 7) << 4;
  const int b0 = l15 * 128 + ((kgrp * 16) ^ x7);  // k-substep 0
  const int b1 = b0 ^ 64;                         // k-substep 1

  f32x4 acc[8];
#pragma unroll
  for (int i = 0; i < 8; ++i) acc[i] = f32x4{0.f, 0.f, 0.f, 0.f};

  float4 A0[4], A1[4];

  auto STAGE = [&](int bufidx, int c) {
    const char* s = wsrc + (size_t)c * CHUNK_BYTES + tid * 16;
#pragma unroll
    for (int q = 0; q < 4; ++q) {
      gload_lds16(s + q * 4096, &lds[bufidx][q * 4096 + wv * 1024]);
    }
  };
  auto LOADA = [&](float4* A, int c) {
    const float* p = aptr + (size_t)c * BK;
    A[0] = *(const float4*)(p);
    A[1] = *(const float4*)(p + 4);
    A[2] = *(const float4*)(p + 32);
    A[3] = *(const float4*)(p + 36);
  };
  auto COMPUTE = [&](int bufidx, const float4* A) {
    const char* pbase = &lds[bufidx][0];
    FragU a0f, a1f;
    a0f.u = u32x4{cvt_pk_bf16(A[0].x, A[0].y), cvt_pk_bf16(A[0].z, A[0].w),
                  cvt_pk_bf16(A[1].x, A[1].y), cvt_pk_bf16(A[1].z, A[1].w)};
    a1f.u = u32x4{cvt_pk_bf16(A[2].x, A[2].y), cvt_pk_bf16(A[2].z, A[2].w),
                  cvt_pk_bf16(A[3].x, A[3].y), cvt_pk_bf16(A[3].z, A[3].w)};
#pragma unroll
    for (int nt = 0; nt < 8; ++nt) {
      FragU bf0, bf1;
      bf0.u = *(const u32x4*)(pbase + nt * 2048 + b0);
      bf1.u = *(const u32x4*)(pbase + nt * 2048 + b1);
      acc[nt] = __builtin_amdgcn_mfma_f32_16x16x32_bf16(a0f.b, bf0.b, acc[nt], 0, 0, 0);
      acc[nt] = __builtin_amdgcn_mfma_f32_16x16x32_bf16(a1f.b, bf1.b, acc[nt], 0, 0, 0);
    }
  };

  // prologue
  LOADA(A0, 0);
  STAGE(0, 0);
  __syncthreads();

#pragma unroll 1
  for (int t = 0; t < NCHUNK; t += 2) {
    STAGE(1, t + 1);
    LOADA(A1, t + 1);
    COMPUTE(0, A0);
    __syncthreads();
    if (t + 2 < NCHUNK) {
      STAGE(0, t + 2);
      LOADA(A0, t + 2);
    }
    COMPUTE(1, A1);
    __syncthreads();
  }

  // epilogue: +be1, relu, @We2, +be2 -> z[rbase .. rbase+15][2]
  float part[4][2];
#pragma unroll
  for (int j = 0; j < 4; ++j) { part[j][0] = 0.f; part[j][1] = 0.f; }
#pragma unroll
  for (int nt = 0; nt < 8; ++nt) {
    int c = nt * 16 + l15;
    float bb = be1[c];
    float w0 = We2[c * 2 + 0];
    float w1 = We2[c * 2 + 1];
#pragma unroll
    for (int j = 0; j < 4; ++j) {
      float h = acc[nt][j] + bb;
      h = h > 0.f ? h : 0.f;
      part[j][0] = fmaf(h, w0, part[j][0]);
      part[j][1] = fmaf(h, w1, part[j][1]);
    }
  }
#pragma unroll
  for (int m = 1; m < 16; m <<= 1) {
#pragma unroll
    for (int j = 0; j < 4; ++j) {
      part[j][0] += __shfl_xor(part[j][0], m, 64);
      part[j][1] += __shfl_xor(part[j][1], m, 64);
    }
  }
  if (l15 == 0) {
    float bz0 = be2[0], bz1 = be2[1];
#pragma unroll
    for (int j = 0; j < 4; ++j) {
      int r = rbase + kgrp * 4 + j;  // C row = (lane>>4)*4 + reg
      float2 zz = make_float2(part[j][0] + bz0, part[j][1] + bz1);
      *(float2*)(zout + (size_t)r * 2) = zz;
    }
  }
}

// ---------------------------------------------------------------------------
// k2: heads — per (row, chunk-of-5-heads) thread, all f32 VALU.
// out = tanh(tanh(h@W2 + b2) + 0.15 * lora),  h = relu(z@W1 + b1)
// ---------------------------------------------------------------------------
__global__ __launch_bounds__(256, 2)
void k2_heads(const float* __restrict__ z,
              const float* __restrict__ W1,
              const float* __restrict__ b1,
              const float* __restrict__ W2,
              const float* __restrict__ b2,
              const float* __restrict__ M,
              float* __restrict__ out) {
  int tid   = blockIdx.x * 256 + threadIdx.x;    // 0 .. 131071
  int chunk = __builtin_amdgcn_readfirstlane(tid >> 15);  // 0..3, wave-uniform
  int row   = tid & (BDIM - 1);

  float2 zz = *(const float2*)(z + (size_t)row * 2);
  float z0 = zz.x, z1 = zz.y;

  int v0 = chunk * 5;
  float* orow = out + (size_t)row * (VHEADS * PDIM) + v0 * PDIM;

#pragma unroll 1
  for (int vi = 0; vi < 5; ++vi) {
    int v = v0 + vi;
    const float* w1a = W1 + (size_t)(v * 2 + 0) * NDIM;
    const float* w1b = W1 + (size_t)(v * 2 + 1) * NDIM;
    const float* bb1 = b1 + (size_t)v * NDIM;
    const float* w2  = W2 + (size_t)v * NDIM * PDIM;

    float p[6] = {0.f, 0.f, 0.f, 0.f, 0.f, 0.f};
#pragma unroll 4
    for (int h = 0; h < NDIM; ++h) {
      float hv = fmaf(z0, w1a[h], fmaf(z1, w1b[h], bb1[h]));
      hv = hv > 0.f ? hv : 0.f;
#pragma unroll
      for (int j = 0; j < 6; ++j) p[j] = fmaf(hv, w2[h * 6 + j], p[j]);
    }
    float o[6];
#pragma unroll
    for (int j = 0; j < 6; ++j) {
      float t1 = fast_tanh(p[j] + b2[v * PDIM + j]);
      float lo = fmaf(z0, M[v * PDIM + j], z1 * M[VHEADS * PDIM + v * PDIM + j]);
      o[j] = fast_tanh(fmaf(0.15f, lo, t1));
    }
    *(float2*)(orow + vi * 6 + 0) = make_float2(o[0], o[1]);
    *(float2*)(orow + vi * 6 + 2) = make_float2(o[2], o[3]);
    *(float2*)(orow + vi * 6 + 4) = make_float2(o[4], o[5]);
  }
}

// ---------------------------------------------------------------------------
extern "C" void kernel_launch(void* const* d_in, const int* in_sizes, int n_in,
                              void* d_out, int out_size, void* d_ws, size_t ws_size,
                              hipStream_t stream) {
  const float* x   = (const float*)d_in[0];
  const float* We1 = (const float*)d_in[1];
  const float* be1 = (const float*)d_in[2];
  const float* We2 = (const float*)d_in[3];
  const float* be2 = (const float*)d_in[4];
  const float* W1  = (const float*)d_in[5];
  const float* b1  = (const float*)d_in[6];
  const float* W2  = (const float*)d_in[7];
  const float* b2  = (const float*)d_in[8];
  const float* lA  = (const float*)d_in[9];
  const float* lB  = (const float*)d_in[10];

  float* out  = (float*)d_out;
  float* zout = out + OUT_ELEMS;                       // second tuple output
  unsigned short* wsw = (unsigned short*)d_ws;         // 512 KB bf16 W images
  float* wsM = (float*)((char*)d_ws + WS_W_BYTES);     // 240 floats

  hipLaunchKernelGGL(k0_prep, dim3(1025), dim3(256), 0, stream,
                     We1, lA, lB, wsw, wsM);
  hipLaunchKernelGGL(k1_encoder, dim3(BDIM / BM), dim3(256), 0, stream,
                     x, wsw, be1, We2, be2, zout);
  hipLaunchKernelGGL(k2_heads, dim3((BDIM * 4) / 256), dim3(256), 0, stream,
                     zout, W1, b1, W2, b2, wsM, out);
}